// Round 8
// baseline (594.673 us; speedup 1.0000x reference)
//
#include <hip/hip_runtime.h>
#include <stdint.h>

typedef __bf16 bf16;
typedef __bf16 bf16x8 __attribute__((ext_vector_type(8)));
typedef float f32x4 __attribute__((ext_vector_type(4)));

__device__ __forceinline__ void gload_lds16(const void* g, void* l) {
    __builtin_amdgcn_global_load_lds(
        (const __attribute__((address_space(1))) unsigned int*)g,
        (__attribute__((address_space(3))) unsigned int*)l, 16, 0, 0);
}

#define BAR()    asm volatile("s_barrier" ::: "memory")
#define WAITV(N) asm volatile("s_waitcnt vmcnt(" #N ")" ::: "memory")

// ============================================================================
// 256x256-tile 8-phase GEMM. C[M,N] = alpha * A[M,K] @ B[N,K]^T (row-major).
// OMODE: 0 = bf16 row-major; 1 = bf16 transposed (VT[z][e][lk], LK=4096);
// 2 = f32 row-major.
// TPB = tiles per block. TPB=2: the tile tail's 7 empty STG slots stage the
// NEXT tile's prologue regions in death-order, so the vmcnt(6) pipeline never
// drains between tiles (silicon-verified race-free in round 5). Tile order is
// the GC-stripe order; with GC=4 consecutive tile ids share the SAME A-panel
// (adjacent B-columns), so tile 2's A re-read is L2-hot — this is the fix for
// round-5's GC=1 regression (FETCH 221 MB -> ~65 MB).
// Epilogues are LDS-free scatters so in-flight next-tile loads never collide.
// ============================================================================
template<int OMODE, int TPB>
__global__ __launch_bounds__(512, 2)
void gemm256(const bf16* __restrict__ A, const bf16* __restrict__ B,
             void* __restrict__ Cv, int K, int N,
             long batchA, long batchB, long batchC, float alpha,
             int nbx, int nby, int GC)
{
    __shared__ __align__(16) bf16 lds[2][4][8192];

    // ---- block remap: bijective XCD swizzle (m204) ----
    const int nwg  = gridDim.x;
    const int orig = blockIdx.x;
    const int q8   = nwg >> 3, r8 = nwg & 7;
    const int xcd  = orig & 7, lid = orig >> 3;
    const int p    = (xcd < r8 ? xcd * (q8 + 1) : r8 * (q8 + 1) + (xcd - r8) * q8) + lid;

    const int t  = threadIdx.x;
    const int l  = t & 63;
    const int w  = t >> 6;
    const int wm = w >> 2;          // 0..1
    const int wn = w & 3;           // 0..3

    // ---- staging lane geometry (pre-swizzled global source, linear LDS) ----
    const int sL   = (t * 16) ^ (((t >> 3) & 3) << 4);
    const int srow = sL >> 6;
    const int sk   = (sL & 63) >> 1;
    const long rstep = 128L * K;
    const int  d0 = t * 8, d1 = t * 8 + 4096;

    // ---- ds_read byte offsets within a 16KB region (swizzled) ----
    const int xl    = ((l >> 1) & 3) << 4;
    const int aBase = ((wm * 128 + (l & 15)) * 64 + ((l >> 4) << 4)) ^ xl;
    const int bBase = ((wn * 64  + (l & 15)) * 64 + ((l >> 4) << 4)) ^ xl;

    const int perb = nbx * nby;
    const int sw   = nby * GC;
    const int NI   = K >> 7;
    const int r0   = (l >> 4) << 2;

#define STG(S, R, G, KOFF) do { \
    const bf16* _g = (G) + (KOFF); \
    gload_lds16(_g,         &lds[S][R][d0]); \
    gload_lds16(_g + rstep, &lds[S][R][d1]); \
  } while (0)

#define RD(S, R, OFF) (*(const bf16x8*)((const char*)&lds[S][R][0] + (OFF)))

#define MM(MB) \
    __builtin_amdgcn_s_setprio(1); \
    _Pragma("unroll") for (int mi = 0; mi < 4; ++mi) \
      _Pragma("unroll") for (int nj = 0; nj < 4; ++nj) \
        acc[MB + mi][nj] = __builtin_amdgcn_mfma_f32_16x16x32_bf16(av[mi], bv[nj], acc[MB + mi][nj], 0, 0, 0); \
    __builtin_amdgcn_s_setprio(0);

#define PH1(S, STGX) { \
    _Pragma("unroll") for (int nj = 0; nj < 4; ++nj) bv[nj] = RD(S, 2, bBase + nj * 1024); \
    _Pragma("unroll") for (int mi = 0; mi < 4; ++mi) av[mi] = RD(S, 0, aBase + mi * 1024); \
    STGX; BAR(); MM(0) BAR(); }

#define PH2(S, STGX) { \
    _Pragma("unroll") for (int mi = 0; mi < 4; ++mi) av[mi] = RD(S, 0, aBase + 4096 + mi * 1024); \
    STGX; BAR(); MM(4) BAR(); }

#define PH3(S, STGX) { \
    _Pragma("unroll") for (int nj = 0; nj < 4; ++nj) bv[nj] = RD(S, 3, bBase + nj * 1024); \
    _Pragma("unroll") for (int mi = 0; mi < 4; ++mi) av[mi] = RD(S, 1, aBase + mi * 1024); \
    STGX; BAR(); MM(0) BAR(); }

#define PH4(S, STGX, WT) { \
    _Pragma("unroll") for (int mi = 0; mi < 4; ++mi) av[mi] = RD(S, 1, aBase + 4096 + mi * 1024); \
    STGX; BAR(); MM(4) WT; BAR(); }

    for (int tt = 0; tt < TPB; ++tt) {
        // ---- decode tile tt in GC-stripe order ----
        const int g   = p * TPB + tt;
        const int z   = g / perb;
        const int pb  = g - z * perb;
        const int st  = pb / sw;
        const int rem = pb - st * sw;
        const int by  = rem / GC;
        const int bx  = st * GC + (rem - by * GC);
        const long rowb = (long)by << 8;
        const long colb = (long)bx << 8;
        const bf16* gA = A + (long)z * batchA + (rowb + srow) * (long)K + sk;
        const bf16* gB = B + (long)z * batchB + (colb + srow) * (long)K + sk;

        // next-tile pointers (for cross-tile tail staging)
        const bf16* gA2 = gA;
        const bf16* gB2 = gB;
        if (TPB > 1 && tt < TPB - 1) {
            const int g2   = g + 1;
            const int z2   = g2 / perb;
            const int pb2  = g2 - z2 * perb;
            const int st2  = pb2 / sw;
            const int rem2 = pb2 - st2 * sw;
            const int by2  = rem2 / GC;
            const int bx2  = st2 * GC + (rem2 - by2 * GC);
            gA2 = A + (long)z2 * batchA + (((long)by2 << 8) + srow) * (long)K + sk;
            gB2 = B + (long)z2 * batchB + (((long)bx2 << 8) + srow) * (long)K + sk;
        }

        f32x4 acc[8][4] = {};
        bf16x8 av[4], bv[4];

        if (tt == 0) {
            STG(0, 0, gA, 0);
            STG(0, 1, gA, 32);
            STG(0, 2, gB, 0);
            STG(0, 3, gB, 32);
            STG(1, 2, gB, 64);
            STG(1, 0, gA, 64);
            STG(1, 3, gB, 96);
            WAITV(6);
            BAR();
        }

        for (int i = 0; i < NI - 1; ++i) {
            const int kb = i << 7;
            const int kn = kb + 128;
            PH1(0, STG(1, 1, gA, kb + 96));
            PH2(0, STG(0, 2, gB, kn));
            PH3(0, STG(0, 0, gA, kn));
            PH4(0, STG(0, 3, gB, kn + 32), WAITV(6));
            PH1(1, STG(0, 1, gA, kn + 32));
            PH2(1, STG(1, 2, gB, kn + 64));
            PH3(1, STG(1, 0, gA, kn + 64));
            PH4(1, STG(1, 3, gB, kn + 96), WAITV(6));
        }
        {
            const int kb = (NI - 1) << 7;
            if (tt < TPB - 1) {
                // cross-tile tail: stage next tile's prologue in death-order
                PH1(0, STG(1, 1, gA, kb + 96));
                PH2(0, STG(0, 2, gB2, 0));
                PH3(0, STG(0, 0, gA2, 0));
                PH4(0, STG(0, 3, gB2, 32), WAITV(6));
                PH1(1, STG(0, 1, gA2, 32));
                PH2(1, STG(1, 2, gB2, 64));
                PH3(1, STG(1, 0, gA2, 64));
                PH4(1, STG(1, 3, gB2, 96), );
            } else {
                PH1(0, STG(1, 1, gA, kb + 96));
                PH2(0, );
                PH3(0, );
                PH4(0, , WAITV(0));
                PH1(1, );
                PH2(1, );
                PH3(1, );
                PH4(1, , );
            }
        }

        // ---- LDS-free scatter epilogue. frag: col=lane&15, row=(l>>4)*4+reg ----
        if constexpr (OMODE == 0) {
            bf16* Cb = (bf16*)Cv + (long)z * batchC;
            const long cb0 = colb + wn * 64 + (l & 15);
            const long rb0 = rowb + wm * 128 + r0;
#pragma unroll
            for (int mf = 0; mf < 8; ++mf)
#pragma unroll
              for (int nj = 0; nj < 4; ++nj) {
                const long col = cb0 + nj * 16;
#pragma unroll
                for (int r = 0; r < 4; ++r)
                    Cb[(rb0 + mf * 16 + r) * (long)N + col] = (bf16)(acc[mf][nj][r] * alpha);
              }
        } else if constexpr (OMODE == 1) {
            // VT[zz][e][lk], LK=4096: 4 consecutive lk -> packed 8B store
            const long e0 = colb + wn * 64 + (l & 15);
            const long rbase = rowb + wm * 128 + r0;
#pragma unroll
            for (int mf = 0; mf < 8; ++mf)
#pragma unroll
              for (int nj = 0; nj < 4; ++nj) {
                const long row = rbase + mf * 16;
                union { bf16 h[4]; uint2 u; } pk;
#pragma unroll
                for (int r = 0; r < 4; ++r) pk.h[r] = (bf16)(acc[mf][nj][r] * alpha);
                *(uint2*)&((bf16*)Cv)[(row >> 12) * 4194304L + (e0 + nj * 16) * 4096L + (row & 4095)] = pk.u;
              }
        } else {
            const long cb0 = colb + wn * 64 + (l & 15);
            const long rb0 = rowb + wm * 128 + r0;
#pragma unroll
            for (int mf = 0; mf < 8; ++mf)
#pragma unroll
              for (int nj = 0; nj < 4; ++nj) {
                const long col = cb0 + nj * 16;
#pragma unroll
                for (int r = 0; r < 4; ++r)
                    ((float*)Cv)[(long)z * batchC + (rb0 + mf * 16 + r) * (long)N + col] = acc[mf][nj][r] * alpha;
              }
        }

        if (TPB > 1 && tt < TPB - 1) { WAITV(6); BAR(); }
    }
#undef STG
#undef RD
#undef MM
#undef PH1
#undef PH2
#undef PH3
#undef PH4
}

// f32 -> bf16, 8 elems/thread (grid-stride)
__global__ void cvt_bf16(const float* __restrict__ in, bf16* __restrict__ out, long n8)
{
    const long stride = (long)gridDim.x * 256;
    for (long i = (long)blockIdx.x * 256 + threadIdx.x; i < n8; i += stride) {
        const float4* p = (const float4*)in + i * 2;
        float4 a = p[0], b = p[1];
        union { bf16 h[8]; uint4 u; } o;
        o.h[0] = (bf16)a.x; o.h[1] = (bf16)a.y; o.h[2] = (bf16)a.z; o.h[3] = (bf16)a.w;
        o.h[4] = (bf16)b.x; o.h[5] = (bf16)b.y; o.h[6] = (bf16)b.z; o.h[7] = (bf16)b.w;
        ((uint4*)out)[i] = o.u;
    }
}

// all 4 weights (each 1M f32) -> contiguous bf16 region
__global__ void cvt_w4(const float* __restrict__ wq, const float* __restrict__ wk,
                       const float* __restrict__ wv, const float* __restrict__ wo,
                       bf16* __restrict__ out)
{
    const long i  = (long)blockIdx.x * 256 + threadIdx.x;
    const int seg = (int)(i >> 17);            // 131072 vec8 per weight
    const long j  = i & 131071;
    const float* src = seg == 0 ? wq : seg == 1 ? wk : seg == 2 ? wv : wo;
    const float4* pp = (const float4*)src + j * 2;
    float4 a = pp[0], b = pp[1];
    union { bf16 h[8]; uint4 u; } o;
    o.h[0] = (bf16)a.x; o.h[1] = (bf16)a.y; o.h[2] = (bf16)a.z; o.h[3] = (bf16)a.w;
    o.h[4] = (bf16)b.x; o.h[5] = (bf16)b.y; o.h[6] = (bf16)b.z; o.h[7] = (bf16)b.w;
    ((uint4*)out)[i] = o.u;
}

// in-place softmax over rows of 4096 bf16; one block (256 thr) per row
__global__ __launch_bounds__(256)
void softmax_rows(bf16* __restrict__ P)
{
    const long base = (long)blockIdx.x * 4096;
    const int t = threadIdx.x;
    union U { uint4 u; bf16 h[8]; };
    U d0, d1;
    d0.u = *(const uint4*)&P[base + t * 8];
    d1.u = *(const uint4*)&P[base + 2048 + t * 8];
    float v[16];
#pragma unroll
    for (int i = 0; i < 8; ++i) { v[i] = (float)d0.h[i]; v[8 + i] = (float)d1.h[i]; }
    float mx = v[0];
#pragma unroll
    for (int i = 1; i < 16; ++i) mx = fmaxf(mx, v[i]);
    for (int o = 32; o; o >>= 1) mx = fmaxf(mx, __shfl_xor(mx, o));
    __shared__ float redm[4], reds[4];
    if ((t & 63) == 0) redm[t >> 6] = mx;
    __syncthreads();
    mx = fmaxf(fmaxf(redm[0], redm[1]), fmaxf(redm[2], redm[3]));
    float s = 0.f;
#pragma unroll
    for (int i = 0; i < 16; ++i) { v[i] = __expf(v[i] - mx); s += v[i]; }
    for (int o = 32; o; o >>= 1) s += __shfl_xor(s, o);
    if ((t & 63) == 0) reds[t >> 6] = s;
    __syncthreads();
    s = reds[0] + reds[1] + reds[2] + reds[3];
    const float inv = 1.f / s;
    U o0, o1;
#pragma unroll
    for (int i = 0; i < 8; ++i) {
        o0.h[i] = (bf16)(v[i] * inv);
        o1.h[i] = (bf16)(v[8 + i] * inv);
    }
    *(uint4*)&P[base + t * 8]        = o0.u;
    *(uint4*)&P[base + 2048 + t * 8] = o1.u;
}

extern "C" void kernel_launch(void* const* d_in, const int* in_sizes, int n_in,
                              void* d_out, int out_size, void* d_ws, size_t ws_size,
                              hipStream_t stream)
{
    (void)in_sizes; (void)n_in; (void)out_size; (void)ws_size;
    const float* T  = (const float*)d_in[0];
    const float* S  = (const float*)d_in[1];
    const float* Wq = (const float*)d_in[2];
    const float* Wk = (const float*)d_in[3];
    const float* Wv = (const float*)d_in[4];
    const float* Wo = (const float*)d_in[5];
    float* Y = (float*)d_out;
    char* ws = (char*)d_ws;

    bf16* Wqb = (bf16*)(ws + 0);           // 4 weights contiguous, 8MB
    bf16* Wkb = (bf16*)(ws + 2097152);
    bf16* Wvb = (bf16*)(ws + 4194304);
    bf16* Wob = (bf16*)(ws + 6291456);
    bf16* Tb  = (bf16*)(ws + 8388608);     // 16MB; reused as O
    bf16* Ob  = Tb;
    bf16* Qb  = (bf16*)(ws + 25165824);    // 16MB
    bf16* Sb  = (bf16*)(ws + 41943040);    // 64MB; reused as P after v-proj
    bf16* Pb  = Sb;
    bf16* Kb  = (bf16*)(ws + 109051904);   // 64MB
    bf16* VTb = (bf16*)(ws + 176160768);   // 64MB (v-proj writes VT directly)

    // converts
    cvt_w4  <<<2048,  256, 0, stream>>>(Wq, Wk, Wv, Wo, Wqb);
    cvt_bf16<<<4096,  256, 0, stream>>>(T, Tb, 1048576);
    cvt_bf16<<<16384, 256, 0, stream>>>(S, Sb, 4194304);

    // q-proj: 128 tiles, TPB=1
    gemm256<0,1><<<128, 512, 0, stream>>>(Tb, Wqb, Qb, 1024, 1024, 0, 0, 0, 1.f, 4, 32, 4);
    // k-proj: 512 tiles -> 256 blocks x 2 A-panel-sharing tiles (GC=4 stripes)
    gemm256<0,2><<<256, 512, 0, stream>>>(Sb, Wkb, Kb, 1024, 1024, 0, 0, 0, 1.f, 4, 128, 4);
    // v-proj -> VT directly, same pairing
    gemm256<1,2><<<256, 512, 0, stream>>>(Sb, Wvb, VTb, 1024, 1024, 0, 0, 0, 1.f, 4, 128, 4);

    // scores = (q k^T) * D^-0.5  [1024 x 4096] x8, 512 tiles -> 256 blocks
    gemm256<0,2><<<256, 512, 0, stream>>>(Qb, Kb, Pb, 1024, 4096,
        1024L * 1024, 4096L * 1024, 1024L * 4096, 0.03125f, 16, 4, 4);

    softmax_rows<<<8192, 256, 0, stream>>>(Pb);

    // O = P V  [1024 x 1024], K=4096 x8, TPB=1 (already at steady pace)
    gemm256<0,1><<<128, 512, 0, stream>>>(Pb, VTb, Ob, 4096, 1024,
        1024L * 4096, 1024L * 4096, 1024L * 1024, 1.f, 4, 4, 4);

    // Y = O Wo^T (fp32 out)
    gemm256<2,1><<<128, 512, 0, stream>>>(Ob, Wob, Y, 1024, 1024, 0, 0, 0, 1.f, 4, 32, 4);
}

// Round 9
// 425.541 us; speedup vs baseline: 1.3975x; 1.3975x over previous
//
#include <hip/hip_runtime.h>
#include <stdint.h>

typedef __bf16 bf16;
typedef __bf16 bf16x8 __attribute__((ext_vector_type(8)));
typedef float f32x4 __attribute__((ext_vector_type(4)));

__device__ __forceinline__ void gload_lds16(const void* g, void* l) {
    __builtin_amdgcn_global_load_lds(
        (const __attribute__((address_space(1))) unsigned int*)g,
        (__attribute__((address_space(3))) unsigned int*)l, 16, 0, 0);
}

#define BAR()    asm volatile("s_barrier" ::: "memory")
#define WAITV(N) asm volatile("s_waitcnt vmcnt(" #N ")" ::: "memory")

// ============================================================================
// 256x256-tile 8-phase GEMM. C[M,N] = alpha * A[M,K] @ B[N,K]^T.
// lda/ldb decoupled from K (split-K support).
// OMODE: 0 = bf16 row-major out (LDS-staged vectorized epilogue);
//        1 = bf16 transposed out (VT[z][e][lk], LK=4096; LDS epilogue);
//        2 = f32 row-major out (scatter; full-line f32 stores);
//        3 = PV split-K=2: half = p>>7, kOff = half*2048, f32 partials out
//            at Cv + half*8388608 + z*1048576 (scatter f32).
// ============================================================================
template<int OMODE>
__global__ __launch_bounds__(512, 2)
void gemm256(const bf16* __restrict__ A, const bf16* __restrict__ B,
             void* __restrict__ Cv, int K, int N,
             long batchA, long batchB, long batchC, float alpha,
             int nbx, int nby, int GC, int lda, int ldb)
{
    __shared__ __align__(16) bf16 lds[2][4][8192];

    // ---- block remap: bijective XCD swizzle (m204) + stripe order ----
    const int nwg  = gridDim.x;
    const int orig = blockIdx.x;
    const int q8   = nwg >> 3, r8 = nwg & 7;
    const int xcd  = orig & 7, lid = orig >> 3;
    const int p    = (xcd < r8 ? xcd * (q8 + 1) : r8 * (q8 + 1) + (xcd - r8) * q8) + lid;

    int pd = p, hv = 0;
    if constexpr (OMODE == 3) { hv = p >> 7; pd = p & 127; }
    const int kOff = hv << 11;          // 0 or 2048

    const int perb = nbx * nby;
    const int z    = pd / perb;
    const int pb   = pd - z * perb;
    const int sw   = nby * GC;
    const int st   = pb / sw;
    const int rem  = pb - st * sw;
    const int by   = rem / GC;
    const int bx   = st * GC + (rem - by * GC);

    const long rowb = (long)by << 8;
    const long colb = (long)bx << 8;

    const int t  = threadIdx.x;
    const int l  = t & 63;
    const int w  = t >> 6;
    const int wm = w >> 2;          // 0..1
    const int wn = w & 3;           // 0..3

    // ---- staging addresses (pre-swizzled global source, linear LDS dest) ----
    const int sL   = (t * 16) ^ (((t >> 3) & 3) << 4);
    const int srow = sL >> 6;
    const int sk   = (sL & 63) >> 1;
    const bf16* gA = A + (long)z * batchA + (rowb + srow) * (long)lda + sk + kOff;
    const bf16* gB = B + (long)z * batchB + (colb + srow) * (long)ldb + sk + kOff;
    const long rA = 128L * lda;
    const long rB = 128L * ldb;
    const int  d0 = t * 8, d1 = t * 8 + 4096;

    // ---- ds_read byte offsets within a 16KB region (swizzled) ----
    const int xl    = ((l >> 1) & 3) << 4;
    const int aBase = ((wm * 128 + (l & 15)) * 64 + ((l >> 4) << 4)) ^ xl;
    const int bBase = ((wn * 64  + (l & 15)) * 64 + ((l >> 4) << 4)) ^ xl;

    f32x4 acc[8][4] = {};
    bf16x8 av[4], bv[4];

#define STG(S, R, G, KOFF2, RS) do { \
    const bf16* _g = (G) + (KOFF2); \
    gload_lds16(_g,      &lds[S][R][d0]); \
    gload_lds16(_g + RS, &lds[S][R][d1]); \
  } while (0)

#define RD(S, R, OFF) (*(const bf16x8*)((const char*)&lds[S][R][0] + (OFF)))

#define MM(MB) \
    __builtin_amdgcn_s_setprio(1); \
    _Pragma("unroll") for (int mi = 0; mi < 4; ++mi) \
      _Pragma("unroll") for (int nj = 0; nj < 4; ++nj) \
        acc[MB + mi][nj] = __builtin_amdgcn_mfma_f32_16x16x32_bf16(av[mi], bv[nj], acc[MB + mi][nj], 0, 0, 0); \
    __builtin_amdgcn_s_setprio(0);

#define PH1(S, STGX) { \
    _Pragma("unroll") for (int nj = 0; nj < 4; ++nj) bv[nj] = RD(S, 2, bBase + nj * 1024); \
    _Pragma("unroll") for (int mi = 0; mi < 4; ++mi) av[mi] = RD(S, 0, aBase + mi * 1024); \
    STGX; BAR(); MM(0) BAR(); }

#define PH2(S, STGX) { \
    _Pragma("unroll") for (int mi = 0; mi < 4; ++mi) av[mi] = RD(S, 0, aBase + 4096 + mi * 1024); \
    STGX; BAR(); MM(4) BAR(); }

#define PH3(S, STGX) { \
    _Pragma("unroll") for (int nj = 0; nj < 4; ++nj) bv[nj] = RD(S, 3, bBase + nj * 1024); \
    _Pragma("unroll") for (int mi = 0; mi < 4; ++mi) av[mi] = RD(S, 1, aBase + mi * 1024); \
    STGX; BAR(); MM(0) BAR(); }

#define PH4(S, STGX, WT) { \
    _Pragma("unroll") for (int mi = 0; mi < 4; ++mi) av[mi] = RD(S, 1, aBase + 4096 + mi * 1024); \
    STGX; BAR(); MM(4) WT; BAR(); }

    // prologue
    STG(0, 0, gA, 0,  rA);
    STG(0, 1, gA, 32, rA);
    STG(0, 2, gB, 0,  rB);
    STG(0, 3, gB, 32, rB);
    STG(1, 2, gB, 64, rB);
    STG(1, 0, gA, 64, rA);
    STG(1, 3, gB, 96, rB);
    WAITV(6);
    BAR();

    const int NI = K >> 7;
    for (int i = 0; i < NI - 1; ++i) {
        const int kb = i << 7;
        const int kn = kb + 128;
        PH1(0, STG(1, 1, gA, kb + 96, rA));
        PH2(0, STG(0, 2, gB, kn,      rB));
        PH3(0, STG(0, 0, gA, kn,      rA));
        PH4(0, STG(0, 3, gB, kn + 32, rB), WAITV(6));
        PH1(1, STG(0, 1, gA, kn + 32, rA));
        PH2(1, STG(1, 2, gB, kn + 64, rB));
        PH3(1, STG(1, 0, gA, kn + 64, rA));
        PH4(1, STG(1, 3, gB, kn + 96, rB), WAITV(6));
    }
    {
        const int kb = (NI - 1) << 7;
        PH1(0, STG(1, 1, gA, kb + 96, rA));
        PH2(0, );
        PH3(0, );
        PH4(0, , WAITV(0));
        PH1(1, );
        PH2(1, );
        PH3(1, );
        PH4(1, , );
    }
#undef STG
#undef RD
#undef MM
#undef PH1
#undef PH2
#undef PH3
#undef PH4

    // ---- epilogue. C/D frag layout: col=lane&15, row=(lane>>4)*4+reg [m89] ----
    const int r0 = (l >> 4) << 2;

    if constexpr (OMODE == 2) {
        // f32 scatter (o-proj): 16 lanes x 4B = full 64-B lines
        const long cb0 = colb + wn * 64 + (l & 15);
        const long rb0 = rowb + wm * 128 + r0;
#pragma unroll
        for (int mf = 0; mf < 8; ++mf)
#pragma unroll
          for (int nj = 0; nj < 4; ++nj) {
            const long col = cb0 + nj * 16;
#pragma unroll
            for (int r = 0; r < 4; ++r) {
                const long row = rb0 + mf * 16 + r;
                ((float*)Cv)[(long)z * batchC + row * (long)N + col] = acc[mf][nj][r] * alpha;
            }
          }
    } else if constexpr (OMODE == 3) {
        // PV split-K partial: f32 scatter to Cv + hv*8M + z*1M
        float* Cb = (float*)Cv + (long)hv * 8388608 + (long)z * 1048576;
        const long cb0 = colb + wn * 64 + (l & 15);
        const long rb0 = rowb + wm * 128 + r0;
#pragma unroll
        for (int mf = 0; mf < 8; ++mf)
#pragma unroll
          for (int nj = 0; nj < 4; ++nj) {
            const long col = cb0 + nj * 16;
#pragma unroll
            for (int r = 0; r < 4; ++r)
                Cb[(rb0 + mf * 16 + r) * 1024 + col] = acc[mf][nj][r];
          }
    } else {
        // vectorized epilogue via LDS [128][280] bf16 (70KB), two halves
        bf16* epi = &lds[0][0][0];
        const int rrow   = t >> 5;          // 0..15
        const int cchunk = (t & 31) << 3;   // 0..248
        const int myh = (OMODE == 0) ? wm : (wn >> 1);
#pragma unroll
        for (int h = 0; h < 2; ++h) {
            if (myh == h) {
#pragma unroll
                for (int mf = 0; mf < 8; ++mf)
#pragma unroll
                  for (int nj = 0; nj < 4; ++nj)
#pragma unroll
                    for (int r = 0; r < 4; ++r) {
                        const float v = acc[mf][nj][r] * alpha;
                        int orow = wm * 128 + mf * 16 + r0 + r;   // C row (local)
                        int ocol = wn * 64 + nj * 16 + (l & 15);  // C col (local)
                        if (OMODE == 1) { int tmp = orow; orow = ocol; ocol = tmp; }
                        epi[(orow - h * 128) * 280 + ocol] = (bf16)v;
                    }
            }
            __syncthreads();
#pragma unroll
            for (int pp = 0; pp < 8; ++pp) {
                const int lrow = pp * 16 + rrow;
                const int row  = h * 128 + lrow;
                uint4 d = *(const uint4*)&epi[lrow * 280 + cchunk];
                if (OMODE == 0) {
                    bf16* Cb = (bf16*)Cv + (long)z * batchC;
                    *(uint4*)&Cb[(rowb + row) * (long)N + colb + cchunk] = d;
                } else {
                    // VT[zz][e][lk], LK=4096, batch rows = 4096
                    const long zz  = rowb >> 12;
                    const long lk0 = (rowb & 4095) + cchunk;
                    *(uint4*)&((bf16*)Cv)[zz * 4194304L + (colb + row) * 4096L + lk0] = d;
                }
            }
            __syncthreads();
        }
    }
}

// f32 -> bf16, 8 elems/thread (grid-stride)
__global__ void cvt_bf16(const float* __restrict__ in, bf16* __restrict__ out, long n8)
{
    const long stride = (long)gridDim.x * 256;
    for (long i = (long)blockIdx.x * 256 + threadIdx.x; i < n8; i += stride) {
        const float4* p = (const float4*)in + i * 2;
        float4 a = p[0], b = p[1];
        union { bf16 h[8]; uint4 u; } o;
        o.h[0] = (bf16)a.x; o.h[1] = (bf16)a.y; o.h[2] = (bf16)a.z; o.h[3] = (bf16)a.w;
        o.h[4] = (bf16)b.x; o.h[5] = (bf16)b.y; o.h[6] = (bf16)b.z; o.h[7] = (bf16)b.w;
        ((uint4*)out)[i] = o.u;
    }
}

// all 4 weights (each 1M f32) -> contiguous bf16 region
__global__ void cvt_w4(const float* __restrict__ wq, const float* __restrict__ wk,
                       const float* __restrict__ wv, const float* __restrict__ wo,
                       bf16* __restrict__ out)
{
    const long i  = (long)blockIdx.x * 256 + threadIdx.x;
    const int seg = (int)(i >> 17);            // 131072 vec8 per weight
    const long j  = i & 131071;
    const float* src = seg == 0 ? wq : seg == 1 ? wk : seg == 2 ? wv : wo;
    const float4* pp = (const float4*)src + j * 2;
    float4 a = pp[0], b = pp[1];
    union { bf16 h[8]; uint4 u; } o;
    o.h[0] = (bf16)a.x; o.h[1] = (bf16)a.y; o.h[2] = (bf16)a.z; o.h[3] = (bf16)a.w;
    o.h[4] = (bf16)b.x; o.h[5] = (bf16)b.y; o.h[6] = (bf16)b.z; o.h[7] = (bf16)b.w;
    ((uint4*)out)[i] = o.u;
}

// Ob = bf16(Pt[0] + Pt[1]); 8M elems, 8/thread
__global__ void reduce_pv(const float* __restrict__ Pt, bf16* __restrict__ Ob)
{
    const long i = (long)blockIdx.x * 256 + threadIdx.x;
    const float4* a = (const float4*)Pt + i * 2;
    const float4* b = (const float4*)(Pt + 8388608) + i * 2;
    float4 x0 = a[0], x1 = a[1], y0 = b[0], y1 = b[1];
    union { bf16 h[8]; uint4 u; } o;
    o.h[0] = (bf16)(x0.x + y0.x); o.h[1] = (bf16)(x0.y + y0.y);
    o.h[2] = (bf16)(x0.z + y0.z); o.h[3] = (bf16)(x0.w + y0.w);
    o.h[4] = (bf16)(x1.x + y1.x); o.h[5] = (bf16)(x1.y + y1.y);
    o.h[6] = (bf16)(x1.z + y1.z); o.h[7] = (bf16)(x1.w + y1.w);
    ((uint4*)Ob)[i] = o.u;
}

// in-place softmax over rows of 4096 bf16; one block (256 thr) per row
__global__ __launch_bounds__(256)
void softmax_rows(bf16* __restrict__ P)
{
    const long base = (long)blockIdx.x * 4096;
    const int t = threadIdx.x;
    union U { uint4 u; bf16 h[8]; };
    U d0, d1;
    d0.u = *(const uint4*)&P[base + t * 8];
    d1.u = *(const uint4*)&P[base + 2048 + t * 8];
    float v[16];
#pragma unroll
    for (int i = 0; i < 8; ++i) { v[i] = (float)d0.h[i]; v[8 + i] = (float)d1.h[i]; }
    float mx = v[0];
#pragma unroll
    for (int i = 1; i < 16; ++i) mx = fmaxf(mx, v[i]);
    for (int o = 32; o; o >>= 1) mx = fmaxf(mx, __shfl_xor(mx, o));
    __shared__ float redm[4], reds[4];
    if ((t & 63) == 0) redm[t >> 6] = mx;
    __syncthreads();
    mx = fmaxf(fmaxf(redm[0], redm[1]), fmaxf(redm[2], redm[3]));
    float s = 0.f;
#pragma unroll
    for (int i = 0; i < 16; ++i) { v[i] = __expf(v[i] - mx); s += v[i]; }
    for (int o = 32; o; o >>= 1) s += __shfl_xor(s, o);
    if ((t & 63) == 0) reds[t >> 6] = s;
    __syncthreads();
    s = reds[0] + reds[1] + reds[2] + reds[3];
    const float inv = 1.f / s;
    U o0, o1;
#pragma unroll
    for (int i = 0; i < 8; ++i) {
        o0.h[i] = (bf16)(v[i] * inv);
        o1.h[i] = (bf16)(v[8 + i] * inv);
    }
    *(uint4*)&P[base + t * 8]        = o0.u;
    *(uint4*)&P[base + 2048 + t * 8] = o1.u;
}

extern "C" void kernel_launch(void* const* d_in, const int* in_sizes, int n_in,
                              void* d_out, int out_size, void* d_ws, size_t ws_size,
                              hipStream_t stream)
{
    (void)in_sizes; (void)n_in; (void)out_size; (void)ws_size;
    const float* T  = (const float*)d_in[0];
    const float* S  = (const float*)d_in[1];
    const float* Wq = (const float*)d_in[2];
    const float* Wk = (const float*)d_in[3];
    const float* Wv = (const float*)d_in[4];
    const float* Wo = (const float*)d_in[5];
    float* Y = (float*)d_out;
    char* ws = (char*)d_ws;

    bf16* Wqb = (bf16*)(ws + 0);           // 4 weights contiguous, 8MB
    bf16* Wkb = (bf16*)(ws + 2097152);
    bf16* Wvb = (bf16*)(ws + 4194304);
    bf16* Wob = (bf16*)(ws + 6291456);
    bf16* Tb  = (bf16*)(ws + 8388608);     // 16MB; reused as O
    bf16* Ob  = Tb;
    bf16* Qb  = (bf16*)(ws + 25165824);    // 16MB
    bf16* Sb  = (bf16*)(ws + 41943040);    // 64MB; reused as P after v-proj
    bf16* Pb  = Sb;
    bf16* Kb  = (bf16*)(ws + 109051904);   // 64MB; reused as f32 PV partials
    float* Pt = (float*)Kb;                //   (K dead after QK)
    bf16* VTb = (bf16*)(ws + 176160768);   // 64MB (v-proj writes VT directly)

    // converts
    cvt_w4  <<<2048,  256, 0, stream>>>(Wq, Wk, Wv, Wo, Wqb);
    cvt_bf16<<<4096,  256, 0, stream>>>(T, Tb, 1048576);
    cvt_bf16<<<16384, 256, 0, stream>>>(S, Sb, 4194304);

    // projections
    gemm256<0><<<128, 512, 0, stream>>>(Tb, Wqb, Qb, 1024, 1024,
        0, 0, 0, 1.f, 4, 32, 4, 1024, 1024);
    gemm256<0><<<512, 512, 0, stream>>>(Sb, Wkb, Kb, 1024, 1024,
        0, 0, 0, 1.f, 4, 128, 4, 1024, 1024);
    // v-proj writes VT[z][e][lk] directly (transposed epilogue)
    gemm256<1><<<512, 512, 0, stream>>>(Sb, Wvb, VTb, 1024, 1024,
        0, 0, 0, 1.f, 4, 128, 4, 1024, 1024);

    // scores = (q k^T) * D^-0.5  [1024 x 4096] x8   (P overwrites Sb region)
    gemm256<0><<<512, 512, 0, stream>>>(Qb, Kb, Pb, 1024, 4096,
        1024L * 1024, 4096L * 1024, 1024L * 4096, 0.03125f, 16, 4, 4, 1024, 1024);

    softmax_rows<<<8192, 256, 0, stream>>>(Pb);

    // O = P V : split-K=2, 256 blocks, f32 partials -> Pt (Kb region)
    gemm256<3><<<256, 512, 0, stream>>>(Pb, VTb, Pt, 2048, 1024,
        1024L * 4096, 1024L * 4096, 1048576, 1.f, 4, 4, 4, 4096, 4096);
    reduce_pv<<<4096, 256, 0, stream>>>(Pt, Ob);

    // Y = O Wo^T (fp32 out)
    gemm256<2><<<128, 512, 0, stream>>>(Ob, Wob, Y, 1024, 1024,
        0, 0, 0, 1.f, 4, 32, 4, 1024, 1024);
}